// Round 2
// 180.215 us; speedup vs baseline: 1.2767x; 1.2767x over previous
//
#include <hip/hip_runtime.h>
#include <math.h>

#define B_  32
#define L_  2048
#define D_  64      // padded head dim (50 -> 64)
#define LOG2E 1.44269504088896340736f

typedef unsigned short u16;
typedef unsigned int u32;
typedef float f32x4 __attribute__((ext_vector_type(4)));
typedef short s16x8 __attribute__((ext_vector_type(8)));
typedef __fp16 h16x2 __attribute__((ext_vector_type(2)));
typedef _Float16 f16x8 __attribute__((ext_vector_type(8)));

// 16B-block XOR swizzle within a 64-u16 (128B) row.
__device__ inline int swz(int row, int blk) { return blk ^ (row & 7); }

__device__ inline float scalar_as_float(const int* p) {
    int v = *p;
    return (v > 0 && v < (1 << 23)) ? (float)v : __int_as_float(v);
}
__device__ inline float fexp2(float x) {
#if __has_builtin(__builtin_amdgcn_exp2f)
    return __builtin_amdgcn_exp2f(x);
#else
    return exp2f(x);
#endif
}
__device__ inline float frcp(float x) {
#if __has_builtin(__builtin_amdgcn_rcpf)
    return __builtin_amdgcn_rcpf(x);
#else
    return 1.0f / x;
#endif
}
__device__ inline float fast_elu(float a) {
    return a > 0.f ? a : fexp2(a * LOG2E) - 1.0f;
}
__device__ inline float fast_tanh(float a) {
    a = fminf(fmaxf(a, -20.f), 20.f);
    const float t = fexp2(a * (2.0f * LOG2E));
    return (t - 1.0f) * frcp(t + 1.0f);
}
// packed f32->f16 (RTZ, hardware): 1 VALU op per 2 elements, lo = a
__device__ inline u32 cvt_pk_f16(float a, float b) {
    union { h16x2 h; u32 u; } cv;
    cv.h = __builtin_amdgcn_cvt_pkrtz(a, b);
    return cv.u;
}
// packed f32->bf16 (RNE, hardware): 1 VALU op per 2 elements, lo = a
__device__ inline u32 cvt_pk_bf16(float a, float b) {
    u32 r;
    asm("v_cvt_pk_bf16_f32 %0, %1, %2" : "=v"(r) : "v"(a), "v"(b));
    return r;
}
__device__ inline f32x4 mfma_bf(s16x8 a, s16x8 b, f32x4 c) {
    return __builtin_amdgcn_mfma_f32_16x16x32_bf16(a, b, c, 0, 0, 0);
}
__device__ inline f32x4 mfma_h(f16x8 a, f16x8 b, f32x4 c) {
    return __builtin_amdgcn_mfma_f32_16x16x32_f16(a, b, c, 0, 0, 0);
}

// -------------------- Kernel 1: projections via fp16 MFMA -------------------
// K,Q: fp16 (scores now carry 2^-10 error vs old perturbed-K bf16 2^-9).
// V: bf16 (unchanged quantization -> same output error floor).
__global__ __launch_bounds__(256)
void kqv_kernel(const float* __restrict__ x,
                const float* __restrict__ Wk, const float* __restrict__ bk,
                const float* __restrict__ Wq, const float* __restrict__ bq,
                const float* __restrict__ Wv, const float* __restrict__ bv,
                const int* __restrict__ slen,
                u16* __restrict__ Kf, u16* __restrict__ Qf,
                u16* __restrict__ Vt)
{
    __shared__ __align__(16) float xs[64 * 65];     // xT fp32, stride 65
    __shared__ __align__(16) u16 ah[64 * 64];       // xT fp16, swizzled
    __shared__ __align__(16) u16 wh[64 * 64];       // W^T fp16, swizzled
    __shared__ float bsh[192];

    const int t = threadIdx.x;
    const int b = blockIdx.y;
    const int l0 = blockIdx.x * 64;
    const int wave = t >> 6;
    const int lane = t & 63;
    const int l15 = lane & 15;
    const int quad = lane >> 4;

    // ---- stage x -> xs transposed [l][c] ----
    #pragma unroll
    for (int it = 0; it < 4; ++it) {
        const int c = (t >> 4) + it * 16;
        const int l4 = (t & 15) * 4;
        const float4 v = *(const float4*)&x[((size_t)b * 64 + c) * L_ + l0 + l4];
        xs[(l4 + 0) * 65 + c] = v.x;
        xs[(l4 + 1) * 65 + c] = v.y;
        xs[(l4 + 2) * 65 + c] = v.z;
        xs[(l4 + 3) * 65 + c] = v.w;
    }
    if (t < 64)       bsh[t] = (t < 50) ? bk[t] : 0.f;
    else if (t < 128) bsh[t] = (t - 64 < 50) ? bq[t - 64] : 0.f;
    else if (t < 192) bsh[t] = bv[t - 128];
    __syncthreads();

    // ---- convert xs -> fp16 A-operand (packed cvt, swizzled rows) ----
    {
        const int l = t >> 2, sg = t & 3;
        const float* xr = &xs[l * 65 + sg * 16];
        union { u32 w[4]; uint4 v; } H0, H1;
        #pragma unroll
        for (int p = 0; p < 4; ++p) {
            H0.w[p] = cvt_pk_f16(xr[2 * p],     xr[2 * p + 1]);
            H1.w[p] = cvt_pk_f16(xr[8 + 2 * p], xr[9 + 2 * p]);
        }
        *(uint4*)(ah + l * 64 + (swz(l, 2 * sg) << 3))     = H0.v;
        *(uint4*)(ah + l * 64 + (swz(l, 2 * sg + 1) << 3)) = H1.v;
    }
    __syncthreads();

    // ---- A fragments, rows l = wave*16 + l15 (persist across phases) ----
    const int arow = wave * 16 + l15;
    const f16x8 a0 = *(const f16x8*)(ah + arow * 64 + (swz(arow, quad) << 3));
    const f16x8 a1 = *(const f16x8*)(ah + arow * 64 + (swz(arow, quad | 4) << 3));

    const float sc2 = rsqrtf(scalar_as_float(slen)) * LOG2E;

    for (int ph = 0; ph < 3; ++ph) {
        __syncthreads();   // previous phase done reading wh
        {
            const int ch = t & 63, c0 = wave * 16;
            const float* W = (ph == 0) ? Wk : (ph == 1) ? Wq : Wv;
            const int wd = (ph == 2) ? 64 : 50;
            #pragma unroll
            for (int j = 0; j < 16; j += 2) {
                const int c = c0 + j;
                const float w0 = (ch < wd) ? W[c * wd + ch] : 0.f;
                const float w1 = (ch < wd) ? W[(c + 1) * wd + ch] : 0.f;
                const int idx = ch * 64 + (swz(ch, c >> 3) << 3) + (c & 7);
                *(u32*)(wh + idx) = cvt_pk_f16(w0, w1);   // c even -> 4B aligned
            }
        }
        __syncthreads();

        #pragma unroll
        for (int ct = 0; ct < 4; ++ct) {
            const int brow = ct * 16 + l15;
            const f16x8 b0 = *(const f16x8*)(wh + brow * 64 + (swz(brow, quad) << 3));
            const f16x8 b1 = *(const f16x8*)(wh + brow * 64 + (swz(brow, quad | 4) << 3));
            const float bb = bsh[ph * 64 + brow];
            f32x4 c = {bb, bb, bb, bb};
            c = mfma_h(a0, b0, c);
            c = mfma_h(a1, b1, c);

            const size_t off0 = ((size_t)b * L_ + l0 + wave * 16 + quad * 4) * D_ + brow;
            if (ph == 0) {
                const u32 k01 = cvt_pk_f16(fast_elu(c[0]), fast_elu(c[1]));
                const u32 k23 = cvt_pk_f16(fast_elu(c[2]), fast_elu(c[3]));
                Kf[off0]          = (u16)k01;
                Kf[off0 + D_]     = (u16)(k01 >> 16);
                Kf[off0 + 2 * D_] = (u16)k23;
                Kf[off0 + 3 * D_] = (u16)(k23 >> 16);
            } else if (ph == 1) {
                const u32 q01 = cvt_pk_f16(fast_elu(c[0]) * sc2, fast_elu(c[1]) * sc2);
                const u32 q23 = cvt_pk_f16(fast_elu(c[2]) * sc2, fast_elu(c[3]) * sc2);
                Qf[off0]          = (u16)q01;
                Qf[off0 + D_]     = (u16)(q01 >> 16);
                Qf[off0 + 2 * D_] = (u16)q23;
                Qf[off0 + 3 * D_] = (u16)(q23 >> 16);
            } else {
                uint2 pv;
                pv.x = cvt_pk_bf16(fast_tanh(c[0]), fast_tanh(c[1]));
                pv.y = cvt_pk_bf16(fast_tanh(c[2]), fast_tanh(c[3]));
                const size_t off = ((size_t)b * 64 + brow) * L_ + l0 + wave * 16 + quad * 4;
                *(uint2*)(Vt + off) = pv;   // 4 consecutive l -> 8B store
            }
        }
    }
}

// -------- Kernel 2: Z[b,m] = sum_l 2^(q_m.k_l); then V[:,m] *= 1/Z[m] ------
__global__ __launch_bounds__(256, 4)
void zsum_kernel(const u16* __restrict__ Kf, const u16* __restrict__ Qf,
                 u16* __restrict__ Vt)
{
    __shared__ __align__(16) u16 kh_s[64 * 64];
    __shared__ float zs[64];

    const int t = threadIdx.x;
    const int b = blockIdx.y;
    const int m0 = blockIdx.x * 64;
    const int wave = t >> 6;
    const int lane = t & 63;
    const int l15 = lane & 15;
    const int quad = lane >> 4;
    const int r = t >> 2, sg = t & 3;

    // A-operand (Q fp16) rows m = m0 + wave*16 + l15, in registers
    const size_t qrow = ((size_t)b * L_ + m0 + wave * 16 + l15) * D_;
    const f16x8 q0 = *(const f16x8*)(Qf + qrow + quad * 8);
    const f16x8 q1 = *(const f16x8*)(Qf + qrow + 32 + quad * 8);

    float zacc[4] = {0.f, 0.f, 0.f, 0.f};

    uint4 rk0, rk1;
    {
        const size_t kb = ((size_t)b * L_ + r) * D_ + sg * 16;
        rk0 = *(const uint4*)(Kf + kb); rk1 = *(const uint4*)(Kf + kb + 8);
    }
    const int lo0 = r * 64 + (swz(r, 2 * sg) << 3);
    const int lo1 = r * 64 + (swz(r, 2 * sg + 1) << 3);

    for (int ch = 0; ch < 32; ++ch) {
        __syncthreads();
        *(uint4*)(kh_s + lo0) = rk0;  *(uint4*)(kh_s + lo1) = rk1;
        __syncthreads();
        if (ch < 31) {
            const size_t kb = ((size_t)b * L_ + (ch + 1) * 64 + r) * D_ + sg * 16;
            rk0 = *(const uint4*)(Kf + kb); rk1 = *(const uint4*)(Kf + kb + 8);
        }
        #pragma unroll
        for (int lt = 0; lt < 4; ++lt) {
            const int row = lt * 16 + l15;
            const f16x8 b0 = *(const f16x8*)(kh_s + row * 64 + (swz(row, quad) << 3));
            const f16x8 b1 = *(const f16x8*)(kh_s + row * 64 + (swz(row, quad | 4) << 3));
            f32x4 s = {0.f, 0.f, 0.f, 0.f};
            s = mfma_h(q0, b0, s);
            s = mfma_h(q1, b1, s);
            #pragma unroll
            for (int i = 0; i < 4; ++i)
                zacc[i] += fexp2(fminf(s[i], 80.f));
        }
    }

    #pragma unroll
    for (int off = 1; off < 16; off <<= 1)
        #pragma unroll
        for (int i = 0; i < 4; ++i)
            zacc[i] += __shfl_xor(zacc[i], off, 64);

    if (l15 == 0) {
        #pragma unroll
        for (int i = 0; i < 4; ++i)
            zs[wave * 16 + quad * 4 + i] = frcp(fmaxf(zacc[i], 1e-30f));
    }
    __syncthreads();

    // normalize this block's V columns in place: V[:, m] *= 1/Z[m]
    {
        const size_t vb = ((size_t)b * 64 + r) * L_ + m0 + sg * 16;
        union { u16 s[16]; u32 w[8]; uint4 v[2]; } V;
        V.v[0] = *(const uint4*)(Vt + vb);
        V.v[1] = *(const uint4*)(Vt + vb + 8);
        #pragma unroll
        for (int p = 0; p < 8; ++p) {
            const float f0 = __uint_as_float((u32)V.s[2 * p]     << 16) * zs[sg * 16 + 2 * p];
            const float f1 = __uint_as_float((u32)V.s[2 * p + 1] << 16) * zs[sg * 16 + 2 * p + 1];
            V.w[p] = cvt_pk_bf16(f0, f1);
        }
        *(uint4*)(Vt + vb)     = V.v[0];
        *(uint4*)(Vt + vb + 8) = V.v[1];
    }
}

// -------- Kernel 3: y[l,c] = sum_m 2^(q_m.k_l) * Vn[m,c]  (V pre-normalized)
__global__ __launch_bounds__(256, 4)
void out_kernel(const u16* __restrict__ Kf, const u16* __restrict__ Qf,
                const u16* __restrict__ Vt, float* __restrict__ out)
{
    __shared__ __align__(16) u16 qh_s[64 * 64];
    __shared__ __align__(16) u16 vn_s[64 * 64];
    __shared__ __align__(16) u16 ph_s[4][16 * 64];   // per-wave P' [l][m] (bf16)

    const int t = threadIdx.x;
    const int b = blockIdx.y;
    const int l0 = blockIdx.x * 64;
    const int wave = t >> 6;
    const int lane = t & 63;
    const int l15 = lane & 15;
    const int quad = lane >> 4;
    const int r = t >> 2, sg = t & 3;
    u16* const ph = ph_s[wave];

    // K fragments (fp16): rows l = l0 + wave*16 + l15, in regs
    const size_t krow = ((size_t)b * L_ + l0 + wave * 16 + l15) * D_;
    const f16x8 k0 = *(const f16x8*)(Kf + krow + quad * 8);
    const f16x8 k1 = *(const f16x8*)(Kf + krow + 32 + quad * 8);

    f32x4 acc[4];
    #pragma unroll
    for (int ct = 0; ct < 4; ++ct) acc[ct] = (f32x4){0.f, 0.f, 0.f, 0.f};

    uint4 rq0, rq1, rv0, rv1;
    {
        const size_t qb = ((size_t)b * L_ + r) * D_ + sg * 16;
        const size_t vb = ((size_t)b * 64 + r) * L_ + sg * 16;
        rq0 = *(const uint4*)(Qf + qb);  rq1 = *(const uint4*)(Qf + qb + 8);
        rv0 = *(const uint4*)(Vt + vb);  rv1 = *(const uint4*)(Vt + vb + 8);
    }
    const int lo0 = r * 64 + (swz(r, 2 * sg) << 3);
    const int lo1 = r * 64 + (swz(r, 2 * sg + 1) << 3);

    for (int ch = 0; ch < 32; ++ch) {
        __syncthreads();
        *(uint4*)(qh_s + lo0) = rq0; *(uint4*)(qh_s + lo1) = rq1;
        *(uint4*)(vn_s + lo0) = rv0; *(uint4*)(vn_s + lo1) = rv1;
        __syncthreads();
        if (ch < 31) {
            const size_t qb = ((size_t)b * L_ + (ch + 1) * 64 + r) * D_ + sg * 16;
            const size_t vb = ((size_t)b * 64 + r) * L_ + (ch + 1) * 64 + sg * 16;
            rq0 = *(const uint4*)(Qf + qb);  rq1 = *(const uint4*)(Qf + qb + 8);
            rv0 = *(const uint4*)(Vt + vb);  rv1 = *(const uint4*)(Vt + vb + 8);
        }

        // scores S[m][l] for 4 m-tiles; P' = 2^S (unnormalized; V carries 1/Z)
        #pragma unroll
        for (int mt = 0; mt < 4; ++mt) {
            const int row = mt * 16 + l15;
            const f16x8 a0 = *(const f16x8*)(qh_s + row * 64 + (swz(row, quad) << 3));
            const f16x8 a1 = *(const f16x8*)(qh_s + row * 64 + (swz(row, quad | 4) << 3));
            f32x4 s = {0.f, 0.f, 0.f, 0.f};
            s = mfma_h(a0, k0, s);
            s = mfma_h(a1, k1, s);
            uint2 p2;
            p2.x = cvt_pk_bf16(fexp2(fminf(s[0], 80.f)), fexp2(fminf(s[1], 80.f)));
            p2.y = cvt_pk_bf16(fexp2(fminf(s[2], 80.f)), fexp2(fminf(s[3], 80.f)));
            const int pw = l15 * 64 + (swz(l15, 2 * mt + (quad >> 1)) << 3) + (quad & 1) * 4;
            *(uint2*)(ph + pw) = p2;
        }

        // PV: rank-64 update of the wave's 16l x 64c tile (bf16, unchanged)
        #pragma unroll
        for (int ks = 0; ks < 2; ++ks) {
            const s16x8 pa = *(const s16x8*)(ph + l15 * 64 + (swz(l15, 4 * ks + quad) << 3));
            #pragma unroll
            for (int ct = 0; ct < 4; ++ct) {
                const int vrow = ct * 16 + l15;
                const s16x8 bvh = *(const s16x8*)(vn_s + vrow * 64 + (swz(vrow, 4 * ks + quad) << 3));
                acc[ct] = mfma_bf(pa, bvh, acc[ct]);
            }
        }
    }

    const int row = l0 + wave * 16 + quad * 4;
    #pragma unroll
    for (int ct = 0; ct < 4; ++ct)
        #pragma unroll
        for (int i = 0; i < 4; ++i)
            out[((size_t)b * L_ + row + i) * 64 + ct * 16 + l15] = acc[ct][i];
}

extern "C" void kernel_launch(void* const* d_in, const int* in_sizes, int n_in,
                              void* d_out, int out_size, void* d_ws, size_t ws_size,
                              hipStream_t stream)
{
    const float* x  = (const float*)d_in[0];
    const float* Wk = (const float*)d_in[1];
    const float* bk = (const float*)d_in[2];
    const float* Wq = (const float*)d_in[3];
    const float* bq = (const float*)d_in[4];
    const float* Wv = (const float*)d_in[5];
    const float* bv = (const float*)d_in[6];
    const int* slen = (const int*)d_in[7];
    float* out = (float*)d_out;

    const size_t n = (size_t)B_ * L_ * D_;   // 3 arrays x 8 MB = 24 MB
    u16* Kf = (u16*)d_ws;
    u16* Qf = Kf + n;
    u16* Vt = Qf + n;

    kqv_kernel<<<dim3(L_ / 64, B_), 256, 0, stream>>>(x, Wk, bk, Wq, bq, Wv, bv,
                                                      slen, Kf, Qf, Vt);
    zsum_kernel<<<dim3(L_ / 64, B_), 256, 0, stream>>>(Kf, Qf, Vt);
    out_kernel<<<dim3(L_ / 64, B_), 256, 0, stream>>>(Kf, Qf, Vt, out);
}